// Round 1
// baseline (264.183 us; speedup 1.0000x reference)
//
#include <hip/hip_runtime.h>
#include <cstdint>
#include <cstddef>

// Problem constants (match reference)
#define BB 64
#define QQ 900
#define DD 256
#define CC 91
#define MM 4500
#define MAXPREV 5

// Output layout (flat float32, concatenated in reference return order)
constexpr size_t OUT_FN   = (size_t)BB * MM * DD;          // after emb
constexpr size_t OUT_TID  = OUT_FN  + (size_t)BB * MM;
constexpr size_t OUT_MASK = OUT_TID + (size_t)BB * MM;
constexpr size_t OUT_NB   = OUT_MASK + (size_t)BB * MM;

// Workspace layout
constexpr size_t WS_MAP   = 0;                              // BB*MM ints
constexpr size_t WS_PFLAG = (size_t)BB * MM * sizeof(int);  // BB*QQ bytes
constexpr size_t WS_FMT   = WS_PFLAG + (size_t)BB * QQ;     // 1 int (aligned: 1,209,600 % 4 == 0)

// Detect whether mem_mask is byte-bools or int32 0/1.
// If int32, every byte at (i & 3) != 0 within the first BB*MM bytes is zero.
__global__ void detect_fmt_kernel(const unsigned char* __restrict__ mask_raw,
                                  int* __restrict__ fmt) {
    __shared__ int s;
    if (threadIdx.x == 0) s = 0;
    __syncthreads();
    int local = 0;
    const int n = BB * MM;  // minimum guaranteed byte size in either format
    for (int i = threadIdx.x; i < n; i += blockDim.x)
        if ((i & 3) && mask_raw[i]) local = 1;
    if (local) atomicOr(&s, 1);
    __syncthreads();
    if (threadIdx.x == 0) *fmt = s;   // 1 => byte-bool format
}

// One wave per (b,q): max over C logits, sigmoid, threshold -> flag byte.
__global__ void __launch_bounds__(256) pred_flag_kernel(
        const float* __restrict__ pred_classes,
        unsigned char* __restrict__ pflag) {
    int row  = blockIdx.x * (blockDim.x >> 6) + (threadIdx.x >> 6);
    int lane = threadIdx.x & 63;
    if (row >= BB * QQ) return;
    const float* p = pred_classes + (size_t)row * CC;
    float m = -3.0e38f;
    if (lane < CC)      m = p[lane];
    if (lane + 64 < CC) m = fmaxf(m, p[lane + 64]);
    #pragma unroll
    for (int off = 32; off > 0; off >>= 1) m = fmaxf(m, __shfl_xor(m, off));
    if (lane == 0) {
        float s = 1.0f / (1.0f + expf(-m));   // matches jax.nn.sigmoid to ~ulps
        pflag[row] = (s >= 0.8f) ? 1 : 0;
    }
}

// One block per batch: stable compaction scan over mem entries, then preds.
// Builds map[b][dest]: -1 = zero slot, code<MM = mem row, code>=MM = pred row (code-MM).
// Also writes fn/tid/mask/nb_items outputs (as float32).
__global__ void __launch_bounds__(256) scan_kernel(
        const int* __restrict__ mem_fn, const int* __restrict__ mem_tid,
        const void* __restrict__ mem_mask, const int* __restrict__ pred_ids,
        const int* __restrict__ cur_frames, const unsigned char* __restrict__ pflag,
        const int* __restrict__ fmt, int* __restrict__ map,
        float* __restrict__ out) {
    const int b = blockIdx.x;
    const int tid = threadIdx.x, lane = tid & 63, wid = tid >> 6;
    const int cf = cur_frames[b];
    const int boolfmt = *fmt;
    const unsigned char* m8  = (const unsigned char*)mem_mask;
    const int*           m32 = (const int*)mem_mask;
    int* mapb = map + (size_t)b * MM;
    __shared__ int wsum[4];

    for (int i = tid; i < MM; i += 256) mapb[i] = -1;
    __syncthreads();

    int base = 0;
    // ---- compact kept memory entries ----
    for (int chunk = 0; chunk < MM; chunk += 256) {
        int i = chunk + tid;
        int flag = 0;
        if (i < MM) {
            int fn = mem_fn[(size_t)b * MM + i];
            int mk = boolfmt ? (m8[(size_t)b * MM + i] != 0)
                             : (m32[(size_t)b * MM + i] != 0);
            flag = (fn > cf - MAXPREV) && mk;
        }
        int incl = flag;
        #pragma unroll
        for (int off = 1; off < 64; off <<= 1) {
            int nv = __shfl_up(incl, off);
            if (lane >= off) incl += nv;
        }
        if (lane == 63) wsum[wid] = incl;
        __syncthreads();
        int woff = 0;
        #pragma unroll
        for (int w = 0; w < 4; w++) if (w < wid) woff += wsum[w];
        int total = wsum[0] + wsum[1] + wsum[2] + wsum[3];
        if (flag) mapb[base + woff + incl - flag] = i;
        base += total;
        __syncthreads();
    }

    // ---- append selected predictions ----
    for (int chunk = 0; chunk < QQ; chunk += 256) {
        int q = chunk + tid;
        int flag = (q < QQ) ? (int)pflag[(size_t)b * QQ + q] : 0;
        int incl = flag;
        #pragma unroll
        for (int off = 1; off < 64; off <<= 1) {
            int nv = __shfl_up(incl, off);
            if (lane >= off) incl += nv;
        }
        if (lane == 63) wsum[wid] = incl;
        __syncthreads();
        int woff = 0;
        #pragma unroll
        for (int w = 0; w < 4; w++) if (w < wid) woff += wsum[w];
        int total = wsum[0] + wsum[1] + wsum[2] + wsum[3];
        int dest = base + woff + incl - flag;
        if (flag && dest < MM) mapb[dest] = MM + q;
        base += total;
        __syncthreads();
    }

    int nb_items = base < MM ? base : MM;
    __syncthreads();  // all map writes visible to block

    float* ofn   = out + OUT_FN   + (size_t)b * MM;
    float* otid  = out + OUT_TID  + (size_t)b * MM;
    float* omask = out + OUT_MASK + (size_t)b * MM;
    for (int d = tid; d < MM; d += 256) {
        int code = mapb[d];
        float fnv = -1.0f, tidv = 0.0f, mkv = 0.0f;
        if (code >= 0) {
            mkv = 1.0f;
            if (code < MM) {
                fnv  = (float)mem_fn[(size_t)b * MM + code];
                tidv = (float)mem_tid[(size_t)b * MM + code];
            } else {
                fnv  = (float)cf;
                tidv = (float)pred_ids[(size_t)b * QQ + (code - MM)];
            }
        }
        ofn[d] = fnv; otid[d] = tidv; omask[d] = mkv;
    }
    if (tid == 0) out[OUT_NB + b] = (float)nb_items;
}

// One wave per output row: gather 256 floats (64 lanes x float4) or zero-fill.
__global__ void __launch_bounds__(256) emb_kernel(
        const float* __restrict__ mem_emb, const float* __restrict__ pred_emb,
        const int* __restrict__ map, float* __restrict__ out) {
    int row  = blockIdx.x * (blockDim.x >> 6) + (threadIdx.x >> 6);
    int lane = threadIdx.x & 63;
    if (row >= BB * MM) return;
    int b = row / MM;
    int code = map[row];
    float4 v = make_float4(0.f, 0.f, 0.f, 0.f);
    if (code >= 0) {
        const float* src = (code < MM)
            ? (mem_emb  + ((size_t)b * MM + code) * DD)
            : (pred_emb + ((size_t)b * QQ + (code - MM)) * DD);
        v = ((const float4*)src)[lane];
    }
    ((float4*)(out + (size_t)row * DD))[lane] = v;
}

extern "C" void kernel_launch(void* const* d_in, const int* in_sizes, int n_in,
                              void* d_out, int out_size, void* d_ws, size_t ws_size,
                              hipStream_t stream) {
    const float* mem_emb    = (const float*)d_in[0];
    const int*   mem_fn     = (const int*)d_in[1];
    const int*   mem_tid    = (const int*)d_in[2];
    const void*  mem_mask   = d_in[3];
    const float* pred_emb   = (const float*)d_in[4];
    const float* pred_cls   = (const float*)d_in[5];
    const int*   pred_ids   = (const int*)d_in[6];
    const int*   cur_frames = (const int*)d_in[7];
    float* out = (float*)d_out;

    int* map             = (int*)((char*)d_ws + WS_MAP);
    unsigned char* pflag = (unsigned char*)d_ws + WS_PFLAG;
    int* fmt             = (int*)((char*)d_ws + WS_FMT);

    detect_fmt_kernel<<<1, 1024, 0, stream>>>((const unsigned char*)mem_mask, fmt);
    pred_flag_kernel<<<(BB * QQ) / 4, 256, 0, stream>>>(pred_cls, pflag);
    scan_kernel<<<BB, 256, 0, stream>>>(mem_fn, mem_tid, mem_mask, pred_ids,
                                        cur_frames, pflag, fmt, map, out);
    emb_kernel<<<(BB * MM) / 4, 256, 0, stream>>>(mem_emb, pred_emb, map, out);
}

// Round 2
// 118.721 us; speedup vs baseline: 2.2252x; 2.2252x over previous
//
#include <hip/hip_runtime.h>
#include <cstdint>
#include <cstddef>

// Problem constants (match reference)
#define BB 64
#define QQ 900
#define DD 256
#define CC 91
#define MM 4500
#define MAXPREV 5

typedef float f4 __attribute__((ext_vector_type(4)));

// Output layout (flat float32, concatenated in reference return order)
constexpr size_t OUT_FN   = (size_t)BB * MM * DD;          // after emb
constexpr size_t OUT_TID  = OUT_FN  + (size_t)BB * MM;
constexpr size_t OUT_MASK = OUT_TID + (size_t)BB * MM;
constexpr size_t OUT_NB   = OUT_MASK + (size_t)BB * MM;

// Workspace layout
constexpr size_t WS_MAP   = 0;                               // BB*MM ints
constexpr size_t WS_PFLAG = (size_t)BB * MM * sizeof(int);   // BB*QQ bytes
constexpr size_t WS_NB    = WS_PFLAG + (size_t)BB * QQ;      // BB ints (offset 1209600, 4-aligned)
constexpr size_t WS_FMT   = WS_NB + (size_t)BB * sizeof(int);// 1 int

// Detect whether mem_mask is byte-bools or int32 0/1.
// If int32 (values 0/1), bytes 1..3 of every word are zero.
__global__ void __launch_bounds__(256) detect_fmt_kernel(
        const uint32_t* __restrict__ w, int* __restrict__ fmt) {
    int i = blockIdx.x * 256 + threadIdx.x;
    const int nw = BB * MM / 4;
    if (i < nw && (w[i] & 0xFFFFFF00u)) atomicOr(fmt, 1);  // 1 => byte-bool format
}

// One wave per (b,q): max over C logits, sigmoid, threshold -> flag byte.
__global__ void __launch_bounds__(256) pred_flag_kernel(
        const float* __restrict__ pred_classes,
        unsigned char* __restrict__ pflag) {
    int row  = blockIdx.x * 4 + (threadIdx.x >> 6);
    int lane = threadIdx.x & 63;
    if (row >= BB * QQ) return;
    const float* p = pred_classes + (size_t)row * CC;
    float m = -3.0e38f;
    if (lane < CC)      m = p[lane];
    if (lane + 64 < CC) m = fmaxf(m, p[lane + 64]);
    #pragma unroll
    for (int off = 32; off > 0; off >>= 1) m = fmaxf(m, __shfl_xor(m, off));
    if (lane == 0) {
        float s = 1.0f / (1.0f + expf(-m));   // matches jax.nn.sigmoid
        pflag[row] = (s >= 0.8f) ? 1 : 0;
    }
}

// One 1024-thread block per batch: stable compaction scan (mem then preds).
// map[b][dest] = source code (code < MM: mem row; >= MM: pred row code-MM).
// Slots >= nb_items are never written NOR read (consumers gate on nb).
__global__ void __launch_bounds__(1024) scan_kernel(
        const int* __restrict__ mem_fn, const void* __restrict__ mem_mask,
        const unsigned char* __restrict__ pflag,
        const int* __restrict__ cur_frames, const int* __restrict__ fmt,
        int* __restrict__ map, int* __restrict__ nbws, float* __restrict__ out) {
    const int b = blockIdx.x;
    const int tid = threadIdx.x, lane = tid & 63, wid = tid >> 6;  // 16 waves
    const int cf = cur_frames[b];
    const int boolfmt = *fmt;
    const unsigned char* m8  = (const unsigned char*)mem_mask;
    const int*           m32 = (const int*)mem_mask;
    int* mapb = map + (size_t)b * MM;
    __shared__ int wsum[16];

    int base = 0;
    // ---- compact kept memory entries (5 chunks of 1024) ----
    #pragma unroll 1
    for (int chunk = 0; chunk < MM; chunk += 1024) {
        int i = chunk + tid;
        int flag = 0;
        if (i < MM) {
            int fn = mem_fn[(size_t)b * MM + i];
            int mk = boolfmt ? (m8[(size_t)b * MM + i] != 0)
                             : (m32[(size_t)b * MM + i] != 0);
            flag = (fn > cf - MAXPREV) && mk;
        }
        int incl = flag;
        #pragma unroll
        for (int off = 1; off < 64; off <<= 1) {
            int nv = __shfl_up(incl, off);
            if (lane >= off) incl += nv;
        }
        if (lane == 63) wsum[wid] = incl;
        __syncthreads();
        int woff = 0, total = 0;
        #pragma unroll
        for (int w = 0; w < 16; w++) { if (w < wid) woff += wsum[w]; total += wsum[w]; }
        if (flag) mapb[base + woff + incl - 1] = i;
        base += total;
        __syncthreads();
    }

    // ---- append selected predictions (QQ=900, single chunk) ----
    {
        int q = tid;
        int flag = (q < QQ) ? (int)pflag[(size_t)b * QQ + q] : 0;
        int incl = flag;
        #pragma unroll
        for (int off = 1; off < 64; off <<= 1) {
            int nv = __shfl_up(incl, off);
            if (lane >= off) incl += nv;
        }
        if (lane == 63) wsum[wid] = incl;
        __syncthreads();
        int woff = 0, total = 0;
        #pragma unroll
        for (int w = 0; w < 16; w++) { if (w < wid) woff += wsum[w]; total += wsum[w]; }
        int dest = base + woff + incl - 1;
        if (flag && dest < MM) mapb[dest] = MM + q;
        base += total;
    }

    if (tid == 0) {
        int nb = base < MM ? base : MM;
        nbws[b] = nb;
        out[OUT_NB + b] = (float)nb;
    }
}

// One wave per output row: gather 256 floats (64 lanes x float4) or zero-fill.
// Lane 0 also writes the fn/tid/mask meta for the row.
__global__ void __launch_bounds__(256) emb_kernel(
        const float* __restrict__ mem_emb, const float* __restrict__ pred_emb,
        const int* __restrict__ mem_fn, const int* __restrict__ mem_tid,
        const int* __restrict__ pred_ids, const int* __restrict__ cur_frames,
        const int* __restrict__ map, const int* __restrict__ nbws,
        float* __restrict__ out) {
    int row  = blockIdx.x * 4 + (threadIdx.x >> 6);   // grid is exact: BB*MM/4 blocks
    int lane = threadIdx.x & 63;
    int b = row / MM;
    int d = row - b * MM;
    int code = (d < nbws[b]) ? map[row] : -1;

    f4 v = (f4)0.0f;
    if (code >= 0) {
        const float* src = (code < MM)
            ? (mem_emb  + ((size_t)b * MM + code) * DD)
            : (pred_emb + ((size_t)b * QQ + (code - MM)) * DD);
        v = __builtin_nontemporal_load((const f4*)src + lane);
    }
    __builtin_nontemporal_store(v, (f4*)(out + (size_t)row * DD) + lane);

    if (lane == 0) {
        float fnv = -1.0f, tidv = 0.0f, mkv = 0.0f;
        if (code >= 0) {
            mkv = 1.0f;
            if (code < MM) {
                fnv  = (float)mem_fn[(size_t)b * MM + code];
                tidv = (float)mem_tid[(size_t)b * MM + code];
            } else {
                fnv  = (float)cur_frames[b];
                tidv = (float)pred_ids[(size_t)b * QQ + (code - MM)];
            }
        }
        out[OUT_FN + row] = fnv;
        out[OUT_TID + row] = tidv;
        out[OUT_MASK + row] = mkv;
    }
}

extern "C" void kernel_launch(void* const* d_in, const int* in_sizes, int n_in,
                              void* d_out, int out_size, void* d_ws, size_t ws_size,
                              hipStream_t stream) {
    const float* mem_emb    = (const float*)d_in[0];
    const int*   mem_fn     = (const int*)d_in[1];
    const int*   mem_tid    = (const int*)d_in[2];
    const void*  mem_mask   = d_in[3];
    const float* pred_emb   = (const float*)d_in[4];
    const float* pred_cls   = (const float*)d_in[5];
    const int*   pred_ids   = (const int*)d_in[6];
    const int*   cur_frames = (const int*)d_in[7];
    float* out = (float*)d_out;

    int* map             = (int*)((char*)d_ws + WS_MAP);
    unsigned char* pflag = (unsigned char*)d_ws + WS_PFLAG;
    int* nbws            = (int*)((char*)d_ws + WS_NB);
    int* fmt             = (int*)((char*)d_ws + WS_FMT);

    hipMemsetAsync(fmt, 0, sizeof(int), stream);
    detect_fmt_kernel<<<(BB * MM / 4 + 255) / 256, 256, 0, stream>>>(
        (const uint32_t*)mem_mask, fmt);
    pred_flag_kernel<<<(BB * QQ) / 4, 256, 0, stream>>>(pred_cls, pflag);
    scan_kernel<<<BB, 1024, 0, stream>>>(mem_fn, mem_mask, pflag, cur_frames,
                                         fmt, map, nbws, out);
    emb_kernel<<<(BB * MM) / 4, 256, 0, stream>>>(mem_emb, pred_emb, mem_fn,
                                                  mem_tid, pred_ids, cur_frames,
                                                  map, nbws, out);
}

// Round 3
// 104.072 us; speedup vs baseline: 2.5385x; 1.1408x over previous
//
#include <hip/hip_runtime.h>
#include <cstdint>
#include <cstddef>

// Problem constants (match reference)
#define BB 64
#define QQ 900
#define DD 256
#define CC 91
#define MM 4500
#define MAXPREV 5

typedef float f4 __attribute__((ext_vector_type(4)));

// Output layout (flat float32, concatenated in reference return order)
constexpr size_t OUT_FN   = (size_t)BB * MM * DD;
constexpr size_t OUT_TID  = OUT_FN  + (size_t)BB * MM;
constexpr size_t OUT_MASK = OUT_TID + (size_t)BB * MM;
constexpr size_t OUT_NB   = OUT_MASK + (size_t)BB * MM;

// Workspace layout
constexpr size_t WS_MAP   = 0;                               // BB*MM ints
constexpr size_t WS_PFLAG = (size_t)BB * MM * sizeof(int);   // BB*QQ bytes
constexpr size_t WS_NB    = WS_PFLAG + (size_t)BB * QQ;      // BB ints

// One wave per (b,q): max over C logits, sigmoid, threshold -> flag byte.
__global__ void __launch_bounds__(256) pred_flag_kernel(
        const float* __restrict__ pred_classes,
        unsigned char* __restrict__ pflag) {
    int row  = blockIdx.x * 4 + (threadIdx.x >> 6);   // grid exact: BB*QQ/4
    int lane = threadIdx.x & 63;
    const float* p = pred_classes + (size_t)row * CC;
    float m = -3.0e38f;
    if (lane < CC)      m = p[lane];
    if (lane + 64 < CC) m = fmaxf(m, p[lane + 64]);
    #pragma unroll
    for (int off = 32; off > 0; off >>= 1) m = fmaxf(m, __shfl_xor(m, off));
    if (lane == 0) {
        float s = 1.0f / (1.0f + expf(-m));   // matches jax.nn.sigmoid
        pflag[row] = (s >= 0.8f) ? 1 : 0;
    }
}

// One 1024-thread block per batch. Inline mask-format detect (redundant,
// L2-shared), 3 stable prefix-scan rounds (4096 mem rows vectorized 4/thread,
// 404-row tail, 900 preds), then fn/tid/mask/nb outputs.
// map[b][dest] = source code (< MM: mem row; >= MM: pred row code-MM).
// Slots >= nb are never written nor read (consumers gate on nb).
__global__ void __launch_bounds__(1024) scan_kernel(
        const int* __restrict__ mem_fn, const int* __restrict__ mem_tid,
        const void* __restrict__ mem_mask, const unsigned char* __restrict__ pflag,
        const int* __restrict__ pred_ids, const int* __restrict__ cur_frames,
        int* __restrict__ map, int* __restrict__ nbws, float* __restrict__ out) {
    const int b = blockIdx.x;
    const int tid = threadIdx.x, lane = tid & 63, wid = tid >> 6;  // 16 waves
    const int cf = cur_frames[b];
    const int thr = cf - MAXPREV;
    int* mapb = map + (size_t)b * MM;
    __shared__ int wsum[16];
    __shared__ int sdet[16];

    // ---- inline format detect: int32 0/1 has bytes 1..3 of every word zero ----
    {
        const uint4* w4 = (const uint4*)mem_mask;
        uint32_t local = 0;
        for (int i = tid; i < (BB * MM / 16); i += 1024) {
            uint4 v = w4[i];
            local |= (v.x | v.y | v.z | v.w) & 0xFFFFFF00u;
        }
        int found = (__ballot(local != 0) != 0ull) ? 1 : 0;
        if (lane == 0) sdet[wid] = found;
    }
    __syncthreads();
    int det = 0;
    #pragma unroll
    for (int w = 0; w < 16; w++) det |= sdet[w];
    const bool boolfmt = det != 0;   // 1 => byte-bool format
    const unsigned char* m8  = (const unsigned char*)mem_mask;
    const int*           m32 = (const int*)mem_mask;

    int base = 0;
    // ---- round A: mem rows 0..4095, 4 per thread (stable within thread) ----
    {
        int4 fn4 = ((const int4*)(mem_fn + (size_t)b * MM))[tid];
        uint32_t mk4;
        if (boolfmt) {
            mk4 = ((const uint32_t*)(m8 + (size_t)b * MM))[tid];
        } else {
            int4 m = ((const int4*)(m32 + (size_t)b * MM))[tid];
            mk4 = (m.x ? 0xFFu : 0) | (m.y ? 0xFF00u : 0) |
                  (m.z ? 0xFF0000u : 0) | (m.w ? 0xFF000000u : 0);
        }
        int f0 = (fn4.x > thr) && (mk4 & 0xFFu);
        int f1 = (fn4.y > thr) && (mk4 & 0xFF00u);
        int f2 = (fn4.z > thr) && (mk4 & 0xFF0000u);
        int f3 = (fn4.w > thr) && (mk4 & 0xFF000000u);
        int cnt = f0 + f1 + f2 + f3;
        int incl = cnt;
        #pragma unroll
        for (int off = 1; off < 64; off <<= 1) {
            int nv = __shfl_up(incl, off);
            if (lane >= off) incl += nv;
        }
        if (lane == 63) wsum[wid] = incl;
        __syncthreads();
        int woff = 0, total = 0;
        #pragma unroll
        for (int w = 0; w < 16; w++) { if (w < wid) woff += wsum[w]; total += wsum[w]; }
        int pos = woff + (incl - cnt);
        int r = 4 * tid;
        if (f0) mapb[pos++] = r;
        if (f1) mapb[pos++] = r + 1;
        if (f2) mapb[pos++] = r + 2;
        if (f3) mapb[pos++] = r + 3;
        base = total;
        __syncthreads();
    }
    // ---- round B: mem rows 4096..4499 ----
    {
        int i = 4096 + tid;
        int flag = 0;
        if (tid < MM - 4096) {
            int fn = mem_fn[(size_t)b * MM + i];
            int mk = boolfmt ? (m8[(size_t)b * MM + i] != 0)
                             : (m32[(size_t)b * MM + i] != 0);
            flag = (fn > thr) && mk;
        }
        int incl = flag;
        #pragma unroll
        for (int off = 1; off < 64; off <<= 1) {
            int nv = __shfl_up(incl, off);
            if (lane >= off) incl += nv;
        }
        if (lane == 63) wsum[wid] = incl;
        __syncthreads();
        int woff = 0, total = 0;
        #pragma unroll
        for (int w = 0; w < 16; w++) { if (w < wid) woff += wsum[w]; total += wsum[w]; }
        if (flag) mapb[base + woff + incl - 1] = i;
        base += total;
        __syncthreads();
    }
    // ---- round C: preds (QQ=900 <= 1024, single round) ----
    {
        int flag = (tid < QQ) ? (int)pflag[(size_t)b * QQ + tid] : 0;
        int incl = flag;
        #pragma unroll
        for (int off = 1; off < 64; off <<= 1) {
            int nv = __shfl_up(incl, off);
            if (lane >= off) incl += nv;
        }
        if (lane == 63) wsum[wid] = incl;
        __syncthreads();
        int woff = 0, total = 0;
        #pragma unroll
        for (int w = 0; w < 16; w++) { if (w < wid) woff += wsum[w]; total += wsum[w]; }
        int dest = base + woff + incl - 1;
        if (flag && dest < MM) mapb[dest] = MM + tid;
        base += total;
    }
    int nb = base < MM ? base : MM;
    __syncthreads();   // all mapb writes visible to block

    // ---- meta outputs (fn/tid/mask as float32) ----
    float* ofn   = out + OUT_FN   + (size_t)b * MM;
    float* otid  = out + OUT_TID  + (size_t)b * MM;
    float* omask = out + OUT_MASK + (size_t)b * MM;
    for (int d = tid; d < MM; d += 1024) {
        int code = (d < nb) ? mapb[d] : -1;
        float fnv = -1.0f, tidv = 0.0f, mkv = 0.0f;
        if (code >= 0) {
            mkv = 1.0f;
            if (code < MM) {
                fnv  = (float)mem_fn[(size_t)b * MM + code];
                tidv = (float)mem_tid[(size_t)b * MM + code];
            } else {
                fnv  = (float)cf;
                tidv = (float)pred_ids[(size_t)b * QQ + (code - MM)];
            }
        }
        ofn[d] = fnv; otid[d] = tidv; omask[d] = mkv;
    }
    if (tid == 0) {
        nbws[b] = nb;
        out[OUT_NB + b] = (float)nb;
    }
}

// One wave per output row: pure gather (64 lanes x float4) or zero-fill.
__global__ void __launch_bounds__(256) emb_kernel(
        const float* __restrict__ mem_emb, const float* __restrict__ pred_emb,
        const int* __restrict__ map, const int* __restrict__ nbws,
        float* __restrict__ out) {
    int row  = blockIdx.x * 4 + (threadIdx.x >> 6);   // grid exact: BB*MM/4
    int lane = threadIdx.x & 63;
    int b = row / MM;
    int d = row - b * MM;
    int code = (d < nbws[b]) ? map[row] : -1;

    f4 v = (f4)0.0f;
    if (code >= 0) {
        const float* src = (code < MM)
            ? (mem_emb  + ((size_t)b * MM + code) * DD)
            : (pred_emb + ((size_t)b * QQ + (code - MM)) * DD);
        v = __builtin_nontemporal_load((const f4*)src + lane);
    }
    __builtin_nontemporal_store(v, (f4*)(out + (size_t)row * DD) + lane);
}

extern "C" void kernel_launch(void* const* d_in, const int* in_sizes, int n_in,
                              void* d_out, int out_size, void* d_ws, size_t ws_size,
                              hipStream_t stream) {
    const float* mem_emb    = (const float*)d_in[0];
    const int*   mem_fn     = (const int*)d_in[1];
    const int*   mem_tid    = (const int*)d_in[2];
    const void*  mem_mask   = d_in[3];
    const float* pred_emb   = (const float*)d_in[4];
    const float* pred_cls   = (const float*)d_in[5];
    const int*   pred_ids   = (const int*)d_in[6];
    const int*   cur_frames = (const int*)d_in[7];
    float* out = (float*)d_out;

    int* map             = (int*)((char*)d_ws + WS_MAP);
    unsigned char* pflag = (unsigned char*)d_ws + WS_PFLAG;
    int* nbws            = (int*)((char*)d_ws + WS_NB);

    pred_flag_kernel<<<(BB * QQ) / 4, 256, 0, stream>>>(pred_cls, pflag);
    scan_kernel<<<BB, 1024, 0, stream>>>(mem_fn, mem_tid, mem_mask, pflag,
                                         pred_ids, cur_frames, map, nbws, out);
    emb_kernel<<<(BB * MM) / 4, 256, 0, stream>>>(mem_emb, pred_emb, map, nbws, out);
}